// Round 2
// baseline (591.735 us; speedup 1.0000x reference)
//
#include <hip/hip_runtime.h>

// Problem constants (fixed by reference setup_inputs):
#define NB    8
#define NA    3
#define GSZ   128
#define NC    (NA*5)            // 15
#define NPRED (NA*GSZ*GSZ)      // 49152 preds per image
#define NTOT  (NB*NPRED)        // 393216
#define MGT   64                // gt rows
#define NWRD  (NPRED/32)        // 1536 mask words per image
#define NEGV  (-1e9f)
#define EPSV  (1e-16f)

// GIoU/IoU exactly mirroring the reference arithmetic order (fp32).
__device__ __forceinline__ void gou_iou(const float4 p, const float4 g,
                                        float& iou, float& gou) {
    float px1 = p.x - p.z * 0.5f, px2 = p.x + p.z * 0.5f;
    float py1 = p.y - p.w * 0.5f, py2 = p.y + p.w * 0.5f;
    float gx1 = g.x - g.z * 0.5f, gx2 = g.x + g.z * 0.5f;
    float gy1 = g.y - g.w * 0.5f, gy2 = g.y + g.w * 0.5f;
    float iw = fmaxf(fminf(px2, gx2) - fmaxf(px1, gx1), 0.0f);
    float ih = fmaxf(fminf(py2, gy2) - fmaxf(py1, gy1), 0.0f);
    float inter = iw * ih;
    float ap = (px2 - px1) * (py2 - py1);
    float ag = (gx2 - gx1) * (gy2 - gy1);
    float un = ap + ag - inter;
    iou = inter / (un + EPSV);
    float cw = fmaxf(px2, gx2) - fminf(px1, gx1);
    float ch = fmaxf(py2, gy2) - fminf(py1, gy1);
    float ac = cw * ch;
    gou = iou - (ac - un) / (ac + EPSV);
}

// K1: decode preds -> pd float4 (x,y,w,h) + conf. Also zero the accumulators.
__global__ __launch_bounds__(256) void k_decode(const float* __restrict__ out,
                                                float4* __restrict__ pd,
                                                float* __restrict__ conf,
                                                double* __restrict__ acc) {
    int idx = blockIdx.x * 256 + threadIdx.x;
    if (blockIdx.x == 0 && threadIdx.x < 16) acc[threadIdx.x] = 0.0;
    if (idx >= NTOT) return;
    int b = idx / NPRED, p = idx % NPRED;
    int a = p / (GSZ * GSZ), r = p % (GSZ * GSZ);
    int y = r / GSZ, x = r % GSZ;
    const float* base = out + ((((size_t)b * NC + a * 5) * GSZ + y) * GSZ + x);
    const int st = GSZ * GSZ;
    float t0 = base[0], t1 = base[st], t2 = base[2 * st], t3 = base[3 * st], t4 = base[4 * st];
    float xs = (tanhf(t0) + 0.5f + (float)x) / (float)GSZ;
    float ys = (tanhf(t1) + 0.5f + (float)y) / (float)GSZ;
    float ws = expf(-t2 * t2);
    float hs = expf(-t3 * t3);
    pd[idx] = make_float4(xs, ys, ws, hs);
    conf[idx] = 1.0f / (1.0f + expf(-t4));
}

// K2: greedy matching, one workgroup per image. All state in LDS.
// Replicates the reference while_loop exactly, incl. argmax first-occurrence
// ties, winner scatter-max conflict resolution, and first-j Amat selection.
#define MTH 1024
__global__ __launch_bounds__(MTH) void k_match(const float* __restrict__ gts,
                                               const float4* __restrict__ pd,
                                               unsigned* __restrict__ tpbits_g,
                                               int* __restrict__ pidx_g,
                                               int* __restrict__ hasgt_g) {
    const int b = blockIdx.x;
    const int tid = threadIdx.x;
    __shared__ unsigned mbits[NWRD];            // matched-pred bitmask
    __shared__ float4 gb[MGT];
    __shared__ int gvalid[MGT], sel[MGT], pdj[MGT], cpd[MGT], cok[MGT];
    __shared__ float valj[MGT], cval[MGT];
    __shared__ float rv[MTH];
    __shared__ int rp[MTH];
    __shared__ int cont;

    for (int i = tid; i < NWRD; i += MTH) mbits[i] = 0u;
    if (tid < MGT) {
        gvalid[tid] = (gts[tid * 5] == (float)b) ? 1 : 0;
        gb[tid] = make_float4(gts[tid * 5 + 1], gts[tid * 5 + 2],
                              gts[tid * 5 + 3], gts[tid * 5 + 4]);
        sel[tid] = 0; cok[tid] = 0; cpd[tid] = 0;
        valj[tid] = NEGV; pdj[tid] = 0; cval[tid] = NEGV;
    }
    __syncthreads();
    if (tid == 0) {
        int hg = 0;
        for (int j = 0; j < MGT; j++) hg |= gvalid[j];
        hasgt_g[b] = hg;
    }

    const float4* pdb = pd + (size_t)b * NPRED;
    for (int it = 0; it < MGT + 2; ++it) {
        __syncthreads();
        if (tid == 0) {
            int c = 0;
            for (int j = 0; j < MGT; j++) if (gvalid[j] && !sel[j]) { c = 1; break; }
            cont = c;
        }
        __syncthreads();
        if (!cont) break;

        // step 1: per active gt, argmax over unmatched preds of gou(p,j).
        // Cache trick: if gt j's previous best pred is still unmatched, its
        // argmax is unchanged (mask only grows) -> skip the rescan.
        for (int j = 0; j < MGT; j++) {
            bool active = gvalid[j] && !sel[j];          // uniform across block
            if (!active) {
                if (tid == 0) { valj[j] = NEGV; pdj[j] = 0; }
                continue;
            }
            if (cok[j]) {
                int pp = cpd[j];
                if (!((mbits[pp >> 5] >> (pp & 31)) & 1u)) {
                    if (tid == 0) { valj[j] = cval[j]; pdj[j] = pp; }
                    continue;
                }
            }
            float4 g = gb[j];
            float bv = NEGV; int bp = 0x7FFFFFFF;
            for (int p = tid; p < NPRED; p += MTH) {
                if ((mbits[p >> 5] >> (p & 31)) & 1u) continue;
                float iu, go; gou_iou(pdb[p], g, iu, go);
                if (go > bv) { bv = go; bp = p; }        // strict > : first max
            }
            rv[tid] = bv; rp[tid] = bp;
            __syncthreads();
            for (int s = MTH / 2; s > 0; s >>= 1) {
                if (tid < s) {
                    float v2 = rv[tid + s]; int p2 = rp[tid + s];
                    if (v2 > rv[tid] || (v2 == rv[tid] && p2 < rp[tid])) {
                        rv[tid] = v2; rp[tid] = p2;
                    }
                }
                __syncthreads();
            }
            if (tid == 0) {
                cval[j] = rv[0]; cpd[j] = rp[0]; cok[j] = 1;
                valj[j] = rv[0]; pdj[j] = rp[0];
            }
            __syncthreads();
        }
        __syncthreads();

        // step 2: conflict resolution (threads 0..63, one per gt).
        if (tid < MGT) {
            int jj = tid;
            if (gvalid[jj] && !sel[jj]) {
                int p = pdj[jj];
                float myv = valj[jj];
                float w = NEGV;
                for (int j2 = 0; j2 < MGT; j2++)
                    if (pdj[j2] == p) w = fmaxf(w, valj[j2]);   // winner[p]
                bool win = (myv >= w) && (w > NEGV * 0.5f);
                if (win) {
                    for (int j2 = 0; j2 < jj; j2++)
                        if (pdj[j2] == p && valj[j2] >= w) { win = false; break; }
                }
                if (win) {
                    atomicOr(&mbits[p >> 5], 1u << (p & 31));
                    sel[jj] = 1;
                    pidx_g[(size_t)b * NPRED + p] = jj;
                }
            }
        }
    }
    __syncthreads();
    for (int i = tid; i < NWRD; i += MTH) tpbits_g[b * NWRD + i] = mbits[i];
}

// K3: fallback argmax for unmatched preds + all loss reductions (fp64 acc).
__global__ __launch_bounds__(256) void k_reduce(const float* __restrict__ gts,
                                                const float4* __restrict__ pd,
                                                const float* __restrict__ conf,
                                                const unsigned* __restrict__ tpbits,
                                                const int* __restrict__ pidx,
                                                const int* __restrict__ hasgt,
                                                double* __restrict__ acc) {
    __shared__ float4 gb[MGT];
    __shared__ float gbatch[MGT];
    int tid = threadIdx.x;
    if (tid < MGT) {
        gbatch[tid] = gts[tid * 5];
        gb[tid] = make_float4(gts[tid * 5 + 1], gts[tid * 5 + 2],
                              gts[tid * 5 + 3], gts[tid * 5 + 4]);
    }
    __syncthreads();
    // s: 0 cnt, 1 sxy, 2 swh, 3 sgou, 4 siou, 5 icnt, 6 sbce, 7 sinter, 8 sarea
    double s[9] = {0, 0, 0, 0, 0, 0, 0, 0, 0};
    for (int idx = blockIdx.x * blockDim.x + tid; idx < NTOT;
         idx += gridDim.x * blockDim.x) {
        int b = idx / NPRED, p = idx % NPRED;
        int tp = (tpbits[b * NWRD + (p >> 5)] >> (p & 31)) & 1;
        int hg = hasgt[b];
        float4 P = pd[idx];
        float pg = 0.0f, pi = 0.0f;
        int j = 0;
        if (hg) {
            if (tp) {
                j = pidx[idx];
            } else {
                float best = NEGV;
                for (int jj = 0; jj < MGT; jj++) {
                    float v = NEGV;
                    if (gbatch[jj] == (float)b) {
                        float iu, go; gou_iou(P, gb[jj], iu, go); v = go;
                    }
                    if (v > best) { best = v; j = jj; }   // first max
                }
            }
            gou_iou(P, gb[j], pi, pg);
        }
        bool thr = pi > 0.5f;
        bool ig = (!thr) || tp;
        float c = conf[idx];
        c = fminf(fmaxf(c, 1e-7f), 1.0f - 1e-7f);
        if (tp) {
            s[0] += 1.0;
            float dx = P.x - gb[j].x, dy = P.y - gb[j].y;
            s[1] += (double)(dx * dx) + (double)(dy * dy);
            float lw = logf(P.z) - logf(gb[j].z);
            float lh = logf(P.w) - logf(gb[j].w);
            s[2] += (double)(lw * lw) + (double)(lh * lh);
            s[3] += (double)pg;
            s[4] += (double)pi;
        }
        if (ig) {
            s[5] += 1.0;
            float bce = tp ? -logf(c) : -log1pf(-c);
            s[6] += (double)bce;
            if (tp) s[7] += (double)c;
            s[8] += (double)c * (double)c;
        }
    }
    // wave-64 shuffle reduce, one fp64 atomic per wave per accumulator
    for (int k = 0; k < 9; k++) {
        double v = s[k];
        for (int off = 32; off > 0; off >>= 1) v += __shfl_down(v, off, 64);
        if ((tid & 63) == 0) atomicAdd(&acc[k], v);
    }
}

// K4: finalize losses and write FLOAT32 outputs (reference returns fp32).
__global__ void k_final(const double* __restrict__ acc,
                        float* __restrict__ o) {
    if (blockIdx.x == 0 && threadIdx.x == 0) {
        double cnt_raw = acc[0];
        double cnt = cnt_raw > 1.0 ? cnt_raw : 1.0;
        double lxy  = acc[1] / cnt;
        double lwh  = acc[2] / cnt;
        double lgou = 1.0 - acc[3] / cnt;
        double liou = 1.0 - acc[4] / cnt;
        double icnt = acc[5] > 1.0 ? acc[5] : 1.0;
        double lbce = acc[6] / icnt;
        // gt_area = (tpf*ig).sum() == raw tp count (ig superset of tp), UNclamped
        double ldice = 1.0 - (2.0 * acc[7] + 1.0) / (acc[8] + cnt_raw + 1.0);
        double lconf = ldice + lbce;
        double tot = lconf + 2.0 * lgou + lwh + lxy;
        o[0] = (float)lxy;
        o[1] = (float)lwh;
        o[2] = (float)lconf;
        o[3] = (float)liou;
        o[4] = (float)lgou;
        o[5] = (float)tot;
    }
}

extern "C" void kernel_launch(void* const* d_in, const int* in_sizes, int n_in,
                              void* d_out, int out_size, void* d_ws, size_t ws_size,
                              hipStream_t stream) {
    const float* out_t = (const float*)d_in[0];  // [8,15,128,128]
    const float* gts   = (const float*)d_in[1];  // [64,5]
    char* ws = (char*)d_ws;
    // workspace layout (all 16-byte aligned):
    double* acc   = (double*)(ws);                 // 128 B (16 doubles)
    int*    hasgt = (int*)(ws + 128);              // 32 B
    size_t off = 256;
    unsigned* tpbits = (unsigned*)(ws + off); off += (size_t)NB * NWRD * 4;  // 49152
    int*      pidx   = (int*)(ws + off);      off += (size_t)NTOT * 4;       // 1572864
    off = (off + 15) & ~(size_t)15;
    float4*   pd     = (float4*)(ws + off);   off += (size_t)NTOT * 16;      // 6291456
    float*    conf   = (float*)(ws + off);    off += (size_t)NTOT * 4;       // 1572864
    float* o = (float*)d_out;

    k_decode<<<NTOT / 256, 256, 0, stream>>>(out_t, pd, conf, acc);
    k_match <<<NB, MTH, 0, stream>>>(gts, pd, tpbits, pidx, hasgt);
    k_reduce<<<512, 256, 0, stream>>>(gts, pd, conf, tpbits, pidx, hasgt, acc);
    k_final <<<1, 64, 0, stream>>>(acc, o);
}

// Round 3
// 179.710 us; speedup vs baseline: 3.2927x; 3.2927x over previous
//
#include <hip/hip_runtime.h>

// Problem constants (fixed by reference setup_inputs):
#define NB    8
#define NA    3
#define GSZ   128
#define NC    (NA*5)            // 15
#define NPRED (NA*GSZ*GSZ)      // 49152 preds per image
#define NTOT  (NB*NPRED)        // 393216
#define MGT   64                // gt rows
#define NWRD  (NPRED/32)        // 1536 mask words per image
#define NEGV  (-1e9f)
#define EPSV  (1e-16f)
#define RBLK  768               // k_reduce blocks (768*256*2 == NTOT)

// GIoU/IoU exactly mirroring the reference arithmetic order (fp32).
__device__ __forceinline__ void gou_iou(const float4 p, const float4 g,
                                        float& iou, float& gou) {
    float px1 = p.x - p.z * 0.5f, px2 = p.x + p.z * 0.5f;
    float py1 = p.y - p.w * 0.5f, py2 = p.y + p.w * 0.5f;
    float gx1 = g.x - g.z * 0.5f, gx2 = g.x + g.z * 0.5f;
    float gy1 = g.y - g.w * 0.5f, gy2 = g.y + g.w * 0.5f;
    float iw = fmaxf(fminf(px2, gx2) - fmaxf(px1, gx1), 0.0f);
    float ih = fmaxf(fminf(py2, gy2) - fmaxf(py1, gy1), 0.0f);
    float inter = iw * ih;
    float ap = (px2 - px1) * (py2 - py1);
    float ag = (gx2 - gx1) * (gy2 - gy1);
    float un = ap + ag - inter;
    iou = inter / (un + EPSV);
    float cw = fmaxf(px2, gx2) - fminf(px1, gx1);
    float ch = fmaxf(py2, gy2) - fminf(py1, gy1);
    float ac = cw * ch;
    gou = iou - (ac - un) / (ac + EPSV);
}

// K1: decode preds -> pd float4 + conf. Block 0 also does gt prep:
// img[j] (owning image or -1), hasgt[b], vcnt[b], vlist[b][...] ascending.
__global__ __launch_bounds__(256) void k_decode(const float* __restrict__ out,
                                                const float* __restrict__ gts,
                                                float4* __restrict__ pd,
                                                float* __restrict__ conf,
                                                int* __restrict__ img,
                                                int* __restrict__ hasgt,
                                                int* __restrict__ vcnt,
                                                int* __restrict__ vlist) {
    int idx = blockIdx.x * 256 + threadIdx.x;
    if (blockIdx.x == 0) {
        int t = threadIdx.x;
        if (t < MGT) {
            float bf = gts[t * 5];
            int im = -1;
            if (bf >= 0.0f && bf < (float)NB) {
                int ib = (int)bf;
                if ((float)ib == bf) im = ib;
            }
            img[t] = im;
        }
        if (t < NB) {
            int c = 0;
            for (int j = 0; j < MGT; j++) {
                float bf = gts[j * 5];
                if (bf == (float)t) { vlist[t * MGT + c] = j; c++; }
            }
            vcnt[t] = c;
            hasgt[t] = (c > 0) ? 1 : 0;
        }
    }
    if (idx >= NTOT) return;
    int b = idx / NPRED, p = idx % NPRED;
    int a = p / (GSZ * GSZ), r = p % (GSZ * GSZ);
    int y = r / GSZ, x = r % GSZ;
    const float* base = out + ((((size_t)b * NC + a * 5) * GSZ + y) * GSZ + x);
    const int st = GSZ * GSZ;
    float t0 = base[0], t1 = base[st], t2 = base[2 * st], t3 = base[3 * st], t4 = base[4 * st];
    float xs = (tanhf(t0) + 0.5f + (float)x) / (float)GSZ;
    float ys = (tanhf(t1) + 0.5f + (float)y) / (float)GSZ;
    float ws = expf(-t2 * t2);
    float hs = expf(-t3 * t3);
    pd[idx] = make_float4(xs, ys, ws, hs);
    conf[idx] = 1.0f / (1.0f + expf(-t4));
}

// K2: round-1 argmax per gt row, one block per gt, massively parallel.
// Mask is empty at round 1, so this IS the initial cached argmax.
__global__ __launch_bounds__(256) void k_scan1(const float* __restrict__ gts,
                                               const int* __restrict__ img,
                                               const float4* __restrict__ pd,
                                               float* __restrict__ cval_g,
                                               int* __restrict__ cpd_g) {
    const int j = blockIdx.x;
    const int tid = threadIdx.x;
    __shared__ float lv[4];
    __shared__ int lp[4];
    int im = img[j];
    if (im < 0) { if (tid == 0) { cval_g[j] = NEGV; cpd_g[j] = 0; } return; }
    float4 g = make_float4(gts[j * 5 + 1], gts[j * 5 + 2], gts[j * 5 + 3], gts[j * 5 + 4]);
    const float4* pdb = pd + (size_t)im * NPRED;
    float bv = NEGV; int bp = 0x7FFFFFFF;
    for (int p = tid; p < NPRED; p += 256) {
        float iu, go; gou_iou(pdb[p], g, iu, go);
        if (go > bv) { bv = go; bp = p; }          // strict > : first max per stripe
    }
    // wave-64 reduce (val desc, idx asc)
    for (int off = 32; off > 0; off >>= 1) {
        float v2 = __shfl_down(bv, off, 64);
        int   p2 = __shfl_down(bp, off, 64);
        if (v2 > bv || (v2 == bv && p2 < bp)) { bv = v2; bp = p2; }
    }
    if ((tid & 63) == 0) { lv[tid >> 6] = bv; lp[tid >> 6] = bp; }
    __syncthreads();
    if (tid == 0) {
        float fv = lv[0]; int fp = lp[0];
        for (int w = 1; w < 4; w++)
            if (lv[w] > fv || (lv[w] == fv && lp[w] < fp)) { fv = lv[w]; fp = lp[w]; }
        cval_g[j] = fv; cpd_g[j] = fp;
    }
}

// K3: greedy matching, one workgroup per image, caches pre-seeded by k_scan1.
// Replicates the reference while_loop exactly (argmax first-occurrence ties,
// winner scatter-max conflict resolution, first-j Amat selection).
#define MTH 1024
__global__ __launch_bounds__(MTH) void k_match(const float* __restrict__ gts,
                                               const int* __restrict__ img,
                                               const float* __restrict__ cval_g,
                                               const int* __restrict__ cpd_g,
                                               const float4* __restrict__ pd,
                                               unsigned* __restrict__ tpbits_g,
                                               int* __restrict__ pidx_g) {
    const int b = blockIdx.x;
    const int tid = threadIdx.x;
    __shared__ unsigned mbits[NWRD];            // matched-pred bitmask
    __shared__ float4 gb[MGT];
    __shared__ int gvalid[MGT], sel[MGT], pdj[MGT], cpd[MGT], cok[MGT];
    __shared__ float valj[MGT], cval[MGT];
    __shared__ float rv[MTH];
    __shared__ int rp[MTH];
    __shared__ int cont;

    for (int i = tid; i < NWRD; i += MTH) mbits[i] = 0u;
    if (tid < MGT) {
        int v = (img[tid] == b) ? 1 : 0;
        gvalid[tid] = v;
        gb[tid] = make_float4(gts[tid * 5 + 1], gts[tid * 5 + 2],
                              gts[tid * 5 + 3], gts[tid * 5 + 4]);
        sel[tid] = 0;
        cok[tid] = v;                           // round-1 argmax pre-seeded
        cpd[tid] = cpd_g[tid];
        cval[tid] = cval_g[tid];
        valj[tid] = NEGV; pdj[tid] = 0;
    }
    __syncthreads();

    const float4* pdb = pd + (size_t)b * NPRED;
    for (int it = 0; it < MGT + 2; ++it) {
        __syncthreads();
        if (tid == 0) {
            int c = 0;
            for (int j = 0; j < MGT; j++) if (gvalid[j] && !sel[j]) { c = 1; break; }
            cont = c;
        }
        __syncthreads();
        if (!cont) break;

        // step 1: per active gt, argmax over unmatched preds of gou(p,j).
        // If gt j's cached best pred is still unmatched, the argmax is
        // unchanged (mask only grows) -> skip the rescan.
        for (int j = 0; j < MGT; j++) {
            bool active = gvalid[j] && !sel[j];          // uniform across block
            if (!active) {
                if (tid == 0) { valj[j] = NEGV; pdj[j] = 0; }
                continue;
            }
            if (cok[j]) {
                int pp = cpd[j];
                if (!((mbits[pp >> 5] >> (pp & 31)) & 1u)) {
                    if (tid == 0) { valj[j] = cval[j]; pdj[j] = pp; }
                    continue;
                }
            }
            float4 g = gb[j];
            float bv = NEGV; int bp = 0x7FFFFFFF;
            for (int p = tid; p < NPRED; p += MTH) {
                if ((mbits[p >> 5] >> (p & 31)) & 1u) continue;
                float iu, go; gou_iou(pdb[p], g, iu, go);
                if (go > bv) { bv = go; bp = p; }        // strict > : first max
            }
            rv[tid] = bv; rp[tid] = bp;
            __syncthreads();
            for (int s = MTH / 2; s > 0; s >>= 1) {
                if (tid < s) {
                    float v2 = rv[tid + s]; int p2 = rp[tid + s];
                    if (v2 > rv[tid] || (v2 == rv[tid] && p2 < rp[tid])) {
                        rv[tid] = v2; rp[tid] = p2;
                    }
                }
                __syncthreads();
            }
            if (tid == 0) {
                cval[j] = rv[0]; cpd[j] = rp[0]; cok[j] = 1;
                valj[j] = rv[0]; pdj[j] = rp[0];
            }
            __syncthreads();
        }
        __syncthreads();

        // step 2: conflict resolution (threads 0..63, one per gt).
        if (tid < MGT) {
            int jj = tid;
            if (gvalid[jj] && !sel[jj]) {
                int p = pdj[jj];
                float myv = valj[jj];
                float w = NEGV;
                for (int j2 = 0; j2 < MGT; j2++)
                    if (pdj[j2] == p) w = fmaxf(w, valj[j2]);   // winner[p]
                bool win = (myv >= w) && (w > NEGV * 0.5f);
                if (win) {
                    for (int j2 = 0; j2 < jj; j2++)
                        if (pdj[j2] == p && valj[j2] >= w) { win = false; break; }
                }
                if (win) {
                    atomicOr(&mbits[p >> 5], 1u << (p & 31));
                    sel[jj] = 1;
                    pidx_g[(size_t)b * NPRED + p] = jj;
                }
            }
        }
    }
    __syncthreads();
    for (int i = tid; i < NWRD; i += MTH) tpbits_g[b * NWRD + i] = mbits[i];
}

// K4: fallback argmax (valid-gt list only) + loss partial sums (fp64),
// block-level reduction to per-block partials (NO global atomics).
__global__ __launch_bounds__(256) void k_reduce(const float* __restrict__ gts,
                                                const float4* __restrict__ pd,
                                                const float* __restrict__ conf,
                                                const unsigned* __restrict__ tpbits,
                                                const int* __restrict__ pidx,
                                                const int* __restrict__ hasgt,
                                                const int* __restrict__ vcnt,
                                                const int* __restrict__ vlist,
                                                double* __restrict__ partial) {
    __shared__ float4 gb[MGT];
    __shared__ int vl_s[NB * MGT];
    __shared__ int vc_s[NB], hg_s[NB];
    __shared__ double wsum[4][9];
    int tid = threadIdx.x;
    if (tid < MGT) {
        gb[tid] = make_float4(gts[tid * 5 + 1], gts[tid * 5 + 2],
                              gts[tid * 5 + 3], gts[tid * 5 + 4]);
    }
    for (int i = tid; i < NB * MGT; i += 256) vl_s[i] = vlist[i];
    if (tid < NB) { vc_s[tid] = vcnt[tid]; hg_s[tid] = hasgt[tid]; }
    __syncthreads();
    // s: 0 cnt, 1 sxy, 2 swh, 3 sgou, 4 siou, 5 icnt, 6 sbce, 7 sinter, 8 sarea
    double s[9] = {0, 0, 0, 0, 0, 0, 0, 0, 0};
    for (int it = 0; it < 2; ++it) {
        int idx = blockIdx.x * 256 + tid + it * (RBLK * 256);
        int b = idx / NPRED, p = idx % NPRED;
        int tp = (tpbits[b * NWRD + (p >> 5)] >> (p & 31)) & 1;
        float4 P = pd[idx];
        float pg = 0.0f, pi = 0.0f;
        int j = 0;
        if (hg_s[b]) {
            if (tp) {
                j = pidx[idx];
            } else {
                float best = NEGV;
                int nv = vc_s[b];
                const int* vl = &vl_s[b * MGT];
                for (int m = 0; m < nv; m++) {
                    int jj = vl[m];                      // ascending j
                    float iu, go; gou_iou(P, gb[jj], iu, go);
                    if (go > best) { best = go; j = jj; }  // first max
                }
            }
            gou_iou(P, gb[j], pi, pg);
        }
        bool thr = pi > 0.5f;
        bool ig = (!thr) || tp;
        float c = conf[idx];
        c = fminf(fmaxf(c, 1e-7f), 1.0f - 1e-7f);
        if (tp) {
            s[0] += 1.0;
            float dx = P.x - gb[j].x, dy = P.y - gb[j].y;
            s[1] += (double)(dx * dx) + (double)(dy * dy);
            float lw = logf(P.z) - logf(gb[j].z);
            float lh = logf(P.w) - logf(gb[j].w);
            s[2] += (double)(lw * lw) + (double)(lh * lh);
            s[3] += (double)pg;
            s[4] += (double)pi;
        }
        if (ig) {
            s[5] += 1.0;
            float bce = tp ? -logf(c) : -log1pf(-c);
            s[6] += (double)bce;
            if (tp) s[7] += (double)c;
            s[8] += (double)c * (double)c;
        }
    }
    // wave-64 shuffle reduce, then cross-wave via LDS, one write per block
    for (int k = 0; k < 9; k++) {
        double v = s[k];
        for (int off = 32; off > 0; off >>= 1) v += __shfl_down(v, off, 64);
        s[k] = v;
    }
    if ((tid & 63) == 0)
        for (int k = 0; k < 9; k++) wsum[tid >> 6][k] = s[k];
    __syncthreads();
    if (tid < 9) {
        double v = wsum[0][tid] + wsum[1][tid] + wsum[2][tid] + wsum[3][tid];
        partial[blockIdx.x * 9 + tid] = v;
    }
}

// K5: reduce per-block partials, finalize losses, write FLOAT32 outputs.
__global__ __launch_bounds__(256) void k_final(const double* __restrict__ partial,
                                               float* __restrict__ o) {
    __shared__ double wsum[4][9];
    int tid = threadIdx.x;
    double s[9] = {0, 0, 0, 0, 0, 0, 0, 0, 0};
    for (int bb = tid; bb < RBLK; bb += 256)
        for (int k = 0; k < 9; k++) s[k] += partial[bb * 9 + k];
    for (int k = 0; k < 9; k++) {
        double v = s[k];
        for (int off = 32; off > 0; off >>= 1) v += __shfl_down(v, off, 64);
        s[k] = v;
    }
    if ((tid & 63) == 0)
        for (int k = 0; k < 9; k++) wsum[tid >> 6][k] = s[k];
    __syncthreads();
    if (tid == 0) {
        double acc[9];
        for (int k = 0; k < 9; k++)
            acc[k] = wsum[0][k] + wsum[1][k] + wsum[2][k] + wsum[3][k];
        double cnt_raw = acc[0];
        double cnt = cnt_raw > 1.0 ? cnt_raw : 1.0;
        double lxy  = acc[1] / cnt;
        double lwh  = acc[2] / cnt;
        double lgou = 1.0 - acc[3] / cnt;
        double liou = 1.0 - acc[4] / cnt;
        double icnt = acc[5] > 1.0 ? acc[5] : 1.0;
        double lbce = acc[6] / icnt;
        // gt_area = (tpf*ig).sum() == raw tp count (ig superset of tp), UNclamped
        double ldice = 1.0 - (2.0 * acc[7] + 1.0) / (acc[8] + cnt_raw + 1.0);
        double lconf = ldice + lbce;
        double tot = lconf + 2.0 * lgou + lwh + lxy;
        o[0] = (float)lxy;
        o[1] = (float)lwh;
        o[2] = (float)lconf;
        o[3] = (float)liou;
        o[4] = (float)lgou;
        o[5] = (float)tot;
    }
}

extern "C" void kernel_launch(void* const* d_in, const int* in_sizes, int n_in,
                              void* d_out, int out_size, void* d_ws, size_t ws_size,
                              hipStream_t stream) {
    const float* out_t = (const float*)d_in[0];  // [8,15,128,128]
    const float* gts   = (const float*)d_in[1];  // [64,5]
    char* ws = (char*)d_ws;
    size_t off = 0;
    double*   partial = (double*)(ws + off);  off += (size_t)RBLK * 9 * 8;   // 55296
    int*      img     = (int*)(ws + off);     off += MGT * 4;
    int*      hasgt   = (int*)(ws + off);     off += NB * 4;
    int*      vcnt    = (int*)(ws + off);     off += NB * 4;
    int*      vlist   = (int*)(ws + off);     off += NB * MGT * 4;
    float*    cval_g  = (float*)(ws + off);   off += MGT * 4;
    int*      cpd_g   = (int*)(ws + off);     off += MGT * 4;
    off = (off + 255) & ~(size_t)255;
    unsigned* tpbits  = (unsigned*)(ws + off); off += (size_t)NB * NWRD * 4; // 49152
    int*      pidx    = (int*)(ws + off);      off += (size_t)NTOT * 4;      // 1.5 MB
    off = (off + 15) & ~(size_t)15;
    float4*   pd      = (float4*)(ws + off);   off += (size_t)NTOT * 16;     // 6.3 MB
    float*    conf    = (float*)(ws + off);    off += (size_t)NTOT * 4;      // 1.5 MB
    float* o = (float*)d_out;

    k_decode<<<NTOT / 256, 256, 0, stream>>>(out_t, gts, pd, conf, img, hasgt, vcnt, vlist);
    k_scan1 <<<MGT, 256, 0, stream>>>(gts, img, pd, cval_g, cpd_g);
    k_match <<<NB, MTH, 0, stream>>>(gts, img, cval_g, cpd_g, pd, tpbits, pidx);
    k_reduce<<<RBLK, 256, 0, stream>>>(gts, pd, conf, tpbits, pidx, hasgt, vcnt, vlist, partial);
    k_final <<<1, 256, 0, stream>>>(partial, o);
}

// Round 4
// 115.730 us; speedup vs baseline: 5.1131x; 1.5528x over previous
//
#include <hip/hip_runtime.h>

// Problem constants (fixed by reference setup_inputs):
#define NB    8
#define NA    3
#define GSZ   128
#define NC    (NA*5)            // 15
#define NPRED (NA*GSZ*GSZ)      // 49152 preds per image
#define NTOT  (NB*NPRED)        // 393216
#define MGT   64                // gt rows
#define NWRD  (NPRED/32)        // 1536 mask words per image
#define NEGV  (-1e9f)
#define EPSV  (1e-16f)
#define RBLK  768               // k_reduce blocks (768*256*2 == NTOT)
#define NCH   16                // scan1 chunks per gt
#define CSZ   (NPRED/NCH)       // 3072 preds per chunk

#define LOG2E 1.442695040888963f
#define LN2   0.693147180559945f

// Fast transcendentals on the gfx950 special-function pipe (~1 ulp).
__device__ __forceinline__ float f_exp(float x)  { return __builtin_amdgcn_exp2f(x * LOG2E); }
__device__ __forceinline__ float f_rcp(float x)  { return __builtin_amdgcn_rcpf(x); }
__device__ __forceinline__ float f_log(float x)  { return __builtin_amdgcn_logf(x) * LN2; }
__device__ __forceinline__ float f_tanh(float x) {
    float e = __builtin_amdgcn_exp2f(x * (2.0f * LOG2E));
    return 1.0f - 2.0f * f_rcp(e + 1.0f);
}
__device__ __forceinline__ float f_sigmoid(float x) {
    return f_rcp(1.0f + __builtin_amdgcn_exp2f(-x * LOG2E));
}

// GIoU/IoU exactly mirroring the reference arithmetic order (fp32).
__device__ __forceinline__ void gou_iou(const float4 p, const float4 g,
                                        float& iou, float& gou) {
    float px1 = p.x - p.z * 0.5f, px2 = p.x + p.z * 0.5f;
    float py1 = p.y - p.w * 0.5f, py2 = p.y + p.w * 0.5f;
    float gx1 = g.x - g.z * 0.5f, gx2 = g.x + g.z * 0.5f;
    float gy1 = g.y - g.w * 0.5f, gy2 = g.y + g.w * 0.5f;
    float iw = fmaxf(fminf(px2, gx2) - fmaxf(px1, gx1), 0.0f);
    float ih = fmaxf(fminf(py2, gy2) - fmaxf(py1, gy1), 0.0f);
    float inter = iw * ih;
    float ap = (px2 - px1) * (py2 - py1);
    float ag = (gx2 - gx1) * (gy2 - gy1);
    float un = ap + ag - inter;
    iou = inter / (un + EPSV);
    float cw = fmaxf(px2, gx2) - fminf(px1, gx1);
    float ch = fmaxf(py2, gy2) - fminf(py1, gy1);
    float ac = cw * ch;
    gou = iou - (ac - un) / (ac + EPSV);
}

// K1: decode preds -> pd float4 + conf (fast transcendentals). Block 0 also
// preps gt metadata: img[j], hasgt[b], vcnt[b], vlist[b][...] (ascending j).
__global__ __launch_bounds__(256) void k_decode(const float* __restrict__ out,
                                                const float* __restrict__ gts,
                                                float4* __restrict__ pd,
                                                float* __restrict__ conf,
                                                int* __restrict__ img,
                                                int* __restrict__ hasgt,
                                                int* __restrict__ vcnt,
                                                int* __restrict__ vlist) {
    int idx = blockIdx.x * 256 + threadIdx.x;
    if (blockIdx.x == 0) {
        int t = threadIdx.x;
        if (t < MGT) {
            float bf = gts[t * 5];
            int im = -1;
            if (bf >= 0.0f && bf < (float)NB) {
                int ib = (int)bf;
                if ((float)ib == bf) im = ib;
            }
            img[t] = im;
        }
        if (t < NB) {
            int c = 0;
            for (int j = 0; j < MGT; j++) {
                float bf = gts[j * 5];
                if (bf == (float)t) { vlist[t * MGT + c] = j; c++; }
            }
            vcnt[t] = c;
            hasgt[t] = (c > 0) ? 1 : 0;
        }
    }
    if (idx >= NTOT) return;
    int b = idx / NPRED, p = idx % NPRED;
    int a = p / (GSZ * GSZ), r = p % (GSZ * GSZ);
    int y = r / GSZ, x = r % GSZ;
    const float* base = out + ((((size_t)b * NC + a * 5) * GSZ + y) * GSZ + x);
    const int st = GSZ * GSZ;
    float t0 = base[0], t1 = base[st], t2 = base[2 * st], t3 = base[3 * st], t4 = base[4 * st];
    const float inv_gs = 1.0f / (float)GSZ;   // exact (pow2)
    float xs = (f_tanh(t0) + 0.5f + (float)x) * inv_gs;
    float ys = (f_tanh(t1) + 0.5f + (float)y) * inv_gs;
    float ws = __builtin_amdgcn_exp2f(-(t2 * t2) * LOG2E);
    float hs = __builtin_amdgcn_exp2f(-(t3 * t3) * LOG2E);
    pd[idx] = make_float4(xs, ys, ws, hs);
    conf[idx] = f_sigmoid(t4);
}

// K2: round-1 argmax per (gt, chunk) — 64*16 = 1024 blocks for occupancy.
// Mask is empty at round 1, so the merged chunks ARE the initial cached argmax.
__global__ __launch_bounds__(256) void k_scan1(const float* __restrict__ gts,
                                               const int* __restrict__ img,
                                               const float4* __restrict__ pd,
                                               float* __restrict__ pval,
                                               int* __restrict__ ppd) {
    const int j  = blockIdx.x / NCH;
    const int ch = blockIdx.x % NCH;
    const int tid = threadIdx.x;
    __shared__ float lv[4];
    __shared__ int lp[4];
    int im = img[j];
    if (im < 0) {
        if (tid == 0) { pval[j * NCH + ch] = NEGV; ppd[j * NCH + ch] = 0; }
        return;
    }
    float4 g = make_float4(gts[j * 5 + 1], gts[j * 5 + 2], gts[j * 5 + 3], gts[j * 5 + 4]);
    const float4* pdb = pd + (size_t)im * NPRED + ch * CSZ;
    float bv = NEGV; int bp = 0x7FFFFFFF;
    #pragma unroll
    for (int k = 0; k < CSZ / 256; k++) {
        int p = tid + k * 256;                 // ascending p per thread
        float iu, go; gou_iou(pdb[p], g, iu, go);
        if (go > bv) { bv = go; bp = p; }      // strict > : first max
    }
    // wave-64 reduce (val desc, idx asc)
    for (int off = 32; off > 0; off >>= 1) {
        float v2 = __shfl_down(bv, off, 64);
        int   p2 = __shfl_down(bp, off, 64);
        if (v2 > bv || (v2 == bv && p2 < bp)) { bv = v2; bp = p2; }
    }
    if ((tid & 63) == 0) { lv[tid >> 6] = bv; lp[tid >> 6] = bp; }
    __syncthreads();
    if (tid == 0) {
        float fv = lv[0]; int fp = lp[0];
        for (int w = 1; w < 4; w++)
            if (lv[w] > fv || (lv[w] == fv && lp[w] < fp)) { fv = lv[w]; fp = lp[w]; }
        pval[j * NCH + ch] = fv;
        ppd[j * NCH + ch]  = fp + ch * CSZ;    // global pred index
    }
}

// K3: greedy matching, one workgroup per image; merges scan1 chunk partials
// to seed the per-gt argmax cache. Replicates the reference while_loop
// exactly (first-occurrence argmax ties, winner scatter-max, first-j Amat).
#define MTH 1024
__global__ __launch_bounds__(MTH) void k_match(const float* __restrict__ gts,
                                               const int* __restrict__ img,
                                               const float* __restrict__ pval,
                                               const int* __restrict__ ppd,
                                               const float4* __restrict__ pd,
                                               unsigned* __restrict__ tpbits_g,
                                               int* __restrict__ pidx_g) {
    const int b = blockIdx.x;
    const int tid = threadIdx.x;
    __shared__ unsigned mbits[NWRD];            // matched-pred bitmask
    __shared__ float4 gb[MGT];
    __shared__ int gvalid[MGT], sel[MGT], pdj[MGT], cpd[MGT], cok[MGT];
    __shared__ float valj[MGT], cval[MGT];
    __shared__ float rv[MTH];
    __shared__ int rp[MTH];
    __shared__ int cont;

    for (int i = tid; i < NWRD; i += MTH) mbits[i] = 0u;
    if (tid < MGT) {
        int v = (img[tid] == b) ? 1 : 0;
        gvalid[tid] = v;
        gb[tid] = make_float4(gts[tid * 5 + 1], gts[tid * 5 + 2],
                              gts[tid * 5 + 3], gts[tid * 5 + 4]);
        sel[tid] = 0;
        cok[tid] = v;                           // round-1 argmax pre-seeded
        // merge chunk partials (ascending chunk = ascending p: strict-> keeps
        // the first occurrence, idx-asc tiebreak for exactness)
        float fv = NEGV; int fp = 0;
        for (int ch = 0; ch < NCH; ch++) {
            float v2 = pval[tid * NCH + ch];
            int   p2 = ppd[tid * NCH + ch];
            if (v2 > fv || (v2 == fv && p2 < fp)) { fv = v2; fp = p2; }
        }
        cval[tid] = fv; cpd[tid] = fp;
        valj[tid] = NEGV; pdj[tid] = 0;
    }
    __syncthreads();

    const float4* pdb = pd + (size_t)b * NPRED;
    for (int it = 0; it < MGT + 2; ++it) {
        __syncthreads();
        if (tid == 0) {
            int c = 0;
            for (int j = 0; j < MGT; j++) if (gvalid[j] && !sel[j]) { c = 1; break; }
            cont = c;
        }
        __syncthreads();
        if (!cont) break;

        // step 1: per active gt, argmax over unmatched preds of gou(p,j).
        // If gt j's cached best pred is still unmatched, the argmax is
        // unchanged (mask only grows) -> skip the rescan.
        for (int j = 0; j < MGT; j++) {
            bool active = gvalid[j] && !sel[j];          // uniform across block
            if (!active) {
                if (tid == 0) { valj[j] = NEGV; pdj[j] = 0; }
                continue;
            }
            if (cok[j]) {
                int pp = cpd[j];
                if (!((mbits[pp >> 5] >> (pp & 31)) & 1u)) {
                    if (tid == 0) { valj[j] = cval[j]; pdj[j] = pp; }
                    continue;
                }
            }
            float4 g = gb[j];
            float bv = NEGV; int bp = 0x7FFFFFFF;
            for (int p = tid; p < NPRED; p += MTH) {
                if ((mbits[p >> 5] >> (p & 31)) & 1u) continue;
                float iu, go; gou_iou(pdb[p], g, iu, go);
                if (go > bv) { bv = go; bp = p; }        // strict > : first max
            }
            rv[tid] = bv; rp[tid] = bp;
            __syncthreads();
            for (int s = MTH / 2; s > 0; s >>= 1) {
                if (tid < s) {
                    float v2 = rv[tid + s]; int p2 = rp[tid + s];
                    if (v2 > rv[tid] || (v2 == rv[tid] && p2 < rp[tid])) {
                        rv[tid] = v2; rp[tid] = p2;
                    }
                }
                __syncthreads();
            }
            if (tid == 0) {
                cval[j] = rv[0]; cpd[j] = rp[0]; cok[j] = 1;
                valj[j] = rv[0]; pdj[j] = rp[0];
            }
            __syncthreads();
        }
        __syncthreads();

        // step 2: conflict resolution (threads 0..63, one per gt).
        if (tid < MGT) {
            int jj = tid;
            if (gvalid[jj] && !sel[jj]) {
                int p = pdj[jj];
                float myv = valj[jj];
                float w = NEGV;
                for (int j2 = 0; j2 < MGT; j2++)
                    if (pdj[j2] == p) w = fmaxf(w, valj[j2]);   // winner[p]
                bool win = (myv >= w) && (w > NEGV * 0.5f);
                if (win) {
                    for (int j2 = 0; j2 < jj; j2++)
                        if (pdj[j2] == p && valj[j2] >= w) { win = false; break; }
                }
                if (win) {
                    atomicOr(&mbits[p >> 5], 1u << (p & 31));
                    sel[jj] = 1;
                    pidx_g[(size_t)b * NPRED + p] = jj;
                }
            }
        }
    }
    __syncthreads();
    for (int i = tid; i < NWRD; i += MTH) tpbits_g[b * NWRD + i] = mbits[i];
}

// K4: fallback argmax (valid-gt list only, carrying iou of the argmax) +
// loss partial sums (fp64), block-reduced to per-block partials (no atomics).
__global__ __launch_bounds__(256) void k_reduce(const float* __restrict__ gts,
                                                const float4* __restrict__ pd,
                                                const float* __restrict__ conf,
                                                const unsigned* __restrict__ tpbits,
                                                const int* __restrict__ pidx,
                                                const int* __restrict__ hasgt,
                                                const int* __restrict__ vcnt,
                                                const int* __restrict__ vlist,
                                                double* __restrict__ partial) {
    __shared__ float4 gb[MGT];
    __shared__ int vl_s[NB * MGT];
    __shared__ int vc_s[NB], hg_s[NB];
    __shared__ double wsum[4][9];
    int tid = threadIdx.x;
    if (tid < MGT) {
        gb[tid] = make_float4(gts[tid * 5 + 1], gts[tid * 5 + 2],
                              gts[tid * 5 + 3], gts[tid * 5 + 4]);
    }
    for (int i = tid; i < NB * MGT; i += 256) vl_s[i] = vlist[i];
    if (tid < NB) { vc_s[tid] = vcnt[tid]; hg_s[tid] = hasgt[tid]; }
    __syncthreads();
    // s: 0 cnt, 1 sxy, 2 swh, 3 sgou, 4 siou, 5 icnt, 6 sbce, 7 sinter, 8 sarea
    double s[9] = {0, 0, 0, 0, 0, 0, 0, 0, 0};
    for (int it = 0; it < 2; ++it) {
        int idx = blockIdx.x * 256 + tid + it * (RBLK * 256);
        int b = idx / NPRED, p = idx % NPRED;
        int tp = (tpbits[b * NWRD + (p >> 5)] >> (p & 31)) & 1;
        float4 P = pd[idx];
        float pg = 0.0f, pi = 0.0f;
        int j = 0;
        if (hg_s[b]) {
            if (tp) {
                j = pidx[idx];
                gou_iou(P, gb[j], pi, pg);
            } else {
                float best = NEGV, besti = 0.0f;
                int nv = vc_s[b];
                const int* vl = &vl_s[b * MGT];
                for (int m = 0; m < nv; m++) {
                    int jj = vl[m];                        // ascending j
                    float iu, go; gou_iou(P, gb[jj], iu, go);
                    if (go > best) { best = go; besti = iu; j = jj; }  // first max
                }
                pg = best; pi = besti;
            }
        }
        bool thr = pi > 0.5f;
        bool ig = (!thr) || tp;
        float c = conf[idx];
        c = fminf(fmaxf(c, 1e-7f), 1.0f - 1e-7f);
        if (tp) {
            s[0] += 1.0;
            float dx = P.x - gb[j].x, dy = P.y - gb[j].y;
            s[1] += (double)(dx * dx) + (double)(dy * dy);
            float lw = f_log(P.z) - f_log(gb[j].z);
            float lh = f_log(P.w) - f_log(gb[j].w);
            s[2] += (double)(lw * lw) + (double)(lh * lh);
            s[3] += (double)pg;
            s[4] += (double)pi;
        }
        if (ig) {
            s[5] += 1.0;
            float bce = tp ? -f_log(c) : -f_log(1.0f - c);
            s[6] += (double)bce;
            if (tp) s[7] += (double)c;
            s[8] += (double)c * (double)c;
        }
    }
    // wave-64 shuffle reduce, then cross-wave via LDS, one write per block
    for (int k = 0; k < 9; k++) {
        double v = s[k];
        for (int off = 32; off > 0; off >>= 1) v += __shfl_down(v, off, 64);
        s[k] = v;
    }
    if ((tid & 63) == 0)
        for (int k = 0; k < 9; k++) wsum[tid >> 6][k] = s[k];
    __syncthreads();
    if (tid < 9) {
        double v = wsum[0][tid] + wsum[1][tid] + wsum[2][tid] + wsum[3][tid];
        partial[blockIdx.x * 9 + tid] = v;
    }
}

// K5: reduce per-block partials, finalize losses, write FLOAT32 outputs.
__global__ __launch_bounds__(256) void k_final(const double* __restrict__ partial,
                                               float* __restrict__ o) {
    __shared__ double wsum[4][9];
    int tid = threadIdx.x;
    double s[9] = {0, 0, 0, 0, 0, 0, 0, 0, 0};
    for (int bb = tid; bb < RBLK; bb += 256)
        for (int k = 0; k < 9; k++) s[k] += partial[bb * 9 + k];
    for (int k = 0; k < 9; k++) {
        double v = s[k];
        for (int off = 32; off > 0; off >>= 1) v += __shfl_down(v, off, 64);
        s[k] = v;
    }
    if ((tid & 63) == 0)
        for (int k = 0; k < 9; k++) wsum[tid >> 6][k] = s[k];
    __syncthreads();
    if (tid == 0) {
        double acc[9];
        for (int k = 0; k < 9; k++)
            acc[k] = wsum[0][k] + wsum[1][k] + wsum[2][k] + wsum[3][k];
        double cnt_raw = acc[0];
        double cnt = cnt_raw > 1.0 ? cnt_raw : 1.0;
        double lxy  = acc[1] / cnt;
        double lwh  = acc[2] / cnt;
        double lgou = 1.0 - acc[3] / cnt;
        double liou = 1.0 - acc[4] / cnt;
        double icnt = acc[5] > 1.0 ? acc[5] : 1.0;
        double lbce = acc[6] / icnt;
        // gt_area = (tpf*ig).sum() == raw tp count (ig superset of tp), UNclamped
        double ldice = 1.0 - (2.0 * acc[7] + 1.0) / (acc[8] + cnt_raw + 1.0);
        double lconf = ldice + lbce;
        double tot = lconf + 2.0 * lgou + lwh + lxy;
        o[0] = (float)lxy;
        o[1] = (float)lwh;
        o[2] = (float)lconf;
        o[3] = (float)liou;
        o[4] = (float)lgou;
        o[5] = (float)tot;
    }
}

extern "C" void kernel_launch(void* const* d_in, const int* in_sizes, int n_in,
                              void* d_out, int out_size, void* d_ws, size_t ws_size,
                              hipStream_t stream) {
    const float* out_t = (const float*)d_in[0];  // [8,15,128,128]
    const float* gts   = (const float*)d_in[1];  // [64,5]
    char* ws = (char*)d_ws;
    size_t off = 0;
    double*   partial = (double*)(ws + off);  off += (size_t)RBLK * 9 * 8;   // 55296
    int*      img     = (int*)(ws + off);     off += MGT * 4;
    int*      hasgt   = (int*)(ws + off);     off += NB * 4;
    int*      vcnt    = (int*)(ws + off);     off += NB * 4;
    int*      vlist   = (int*)(ws + off);     off += NB * MGT * 4;
    float*    pval    = (float*)(ws + off);   off += MGT * NCH * 4;
    int*      ppd     = (int*)(ws + off);     off += MGT * NCH * 4;
    off = (off + 255) & ~(size_t)255;
    unsigned* tpbits  = (unsigned*)(ws + off); off += (size_t)NB * NWRD * 4; // 49152
    int*      pidx    = (int*)(ws + off);      off += (size_t)NTOT * 4;      // 1.5 MB
    off = (off + 15) & ~(size_t)15;
    float4*   pd      = (float4*)(ws + off);   off += (size_t)NTOT * 16;     // 6.3 MB
    float*    conf    = (float*)(ws + off);    off += (size_t)NTOT * 4;      // 1.5 MB
    float* o = (float*)d_out;

    k_decode<<<NTOT / 256, 256, 0, stream>>>(out_t, gts, pd, conf, img, hasgt, vcnt, vlist);
    k_scan1 <<<MGT * NCH, 256, 0, stream>>>(gts, img, pd, pval, ppd);
    k_match <<<NB, MTH, 0, stream>>>(gts, img, pval, ppd, pd, tpbits, pidx);
    k_reduce<<<RBLK, 256, 0, stream>>>(gts, pd, conf, tpbits, pidx, hasgt, vcnt, vlist, partial);
    k_final <<<1, 256, 0, stream>>>(partial, o);
}